// Round 16
// baseline (208.858 us; speedup 1.0000x reference)
//
#include <hip/hip_runtime.h>
#include <hip/hip_bf16.h>
#include <float.h>

#define F_DIM 64
#define H_DIM 128
#define LW2   104   // wt2 row stride (bf16) for K=96 [x[e0]|ppf|pad]: 208 B, 16B-aligned
#define LW1   72    // w1t row stride (bf16) for K=64 [x[e1]]: 144 B, 16B-aligned
#define NB    128   // histogram blocks (counting-sort partitions)
#define SB    128   // streaming-role blocks fused into histx (idle half of the chip)
#define SMAX  25600 // max slots supported by the LDS histogram (100 KB of 160 KB/CU)

typedef __attribute__((ext_vector_type(8))) short short8;   // 8 bf16 (mfma A/B frag)
typedef __attribute__((ext_vector_type(4))) float f32x4;    // mfma C/D frag

__device__ __forceinline__ unsigned short f2bf(float f) {
    __hip_bfloat16 h = __float2bfloat16(f);
    return __builtin_bit_cast(unsigned short, h);
}
__device__ __forceinline__ unsigned pk(float a, float b) {
    return (unsigned)f2bf(a) | ((unsigned)f2bf(b) << 16);
}

__device__ __forceinline__ float angle3(float ax, float ay, float az,
                                        float bx, float by, float bz) {
    float cx = ay*bz - az*by;
    float cy = az*bx - ax*bz;
    float cz = ax*by - ay*bx;
    float cn = sqrtf(cx*cx + cy*cy + cz*cz);
    float d  = ax*bx + ay*by + az*bz;
    return atan2f(cn, d);
}

// tiny prerequisite pass: only what hist needs (node2slot) + small builds + pos tail.
__global__ __launch_bounds__(256)
void prep_tiny(const float* __restrict__ W, unsigned short* __restrict__ wt2,
               unsigned short* __restrict__ w1t, const int* __restrict__ idx,
               int* __restrict__ node2slot, const float* __restrict__ pos,
               float* __restrict__ out, int S) {
    const int T = gridDim.x * blockDim.x;
    const int gid = blockIdx.x * blockDim.x + threadIdx.x;
    for (int g = gid; g < H_DIM * LW2; g += T) {          // W rows 64..131 -> [H][LW2]
        int h = g / LW2, k = g % LW2;
        float v = 0.f;
        if (k < F_DIM)          v = W[(F_DIM + k) * H_DIM + h];
        else if (k < F_DIM + 4) v = W[(2 * F_DIM + (k - F_DIM)) * H_DIM + h];
        wt2[g] = f2bf(v);
    }
    for (int g = gid; g < H_DIM * LW1; g += T) {          // W rows 0..63 -> [H][LW1]
        int h = g / LW1, k = g % LW1;
        w1t[g] = f2bf((k < F_DIM) ? W[k * H_DIM + h] : 0.f);
    }
    for (int g = gid; g < S; g += T) node2slot[idx[g]] = g;  // any winner = canonical slot
    for (int g = gid; g < 3 * S; g += T)                     // out tail = pos[idx]
        out[(size_t)S * H_DIM + g] = pos[(size_t)idx[g / 3] * 3 + (g % 3)];
}

// role-split kernel: blocks [0,NB) = block-local LDS histogram (fast atomics, return =
// local rank -> stable counting sort phase 1); blocks [NB,NB+SB) = streaming (xbf
// conversion + pn packing) on the otherwise-idle half of the chip.
__global__ __launch_bounds__(1024)
void histx(const int* __restrict__ edge, const int* __restrict__ node2slot,
           unsigned short* __restrict__ rank16, int* __restrict__ counts,
           int* __restrict__ total, const float* __restrict__ x,
           unsigned short* __restrict__ xbf, const float* __restrict__ pos,
           const float* __restrict__ normal, float* __restrict__ pn,
           int E, int S, int chunk, int N, int NF8) {
    __shared__ int hcnt[SMAX];
    if ((int)blockIdx.x >= NB) {
        // ---- streaming role ----
        const int T2 = SB * 1024;
        const int g0 = (blockIdx.x - NB) * 1024 + threadIdx.x;
        for (int g = g0; g < NF8; g += T2) {              // x[N][64] f32 -> bf16, 8/thread
            const float4* s4 = (const float4*)x + (size_t)g * 2;
            float4 f0 = s4[0], f1 = s4[1];
            uint4 q;
            q.x = pk(f0.x, f0.y); q.y = pk(f0.z, f0.w);
            q.z = pk(f1.x, f1.y); q.w = pk(f1.z, f1.w);
            ((uint4*)xbf)[g] = q;
        }
        for (int g = g0; g < N; g += T2) {                // pn[g] = {pos.xyz, nrm.xyz,0,0}
            float4 q0, q1;
            q0.x = pos[3*g]; q0.y = pos[3*g+1]; q0.z = pos[3*g+2]; q0.w = normal[3*g];
            q1.x = normal[3*g+1]; q1.y = normal[3*g+2]; q1.z = 0.f; q1.w = 0.f;
            ((float4*)pn)[(size_t)g * 2]     = q0;
            ((float4*)pn)[(size_t)g * 2 + 1] = q1;
        }
        return;
    }
    // ---- histogram role ----
    if (blockIdx.x == 0 && threadIdx.x == 0) *total = 0;
    for (int i = threadIdx.x; i < S; i += 1024) hcnt[i] = 0;
    __syncthreads();
    const int base = blockIdx.x * chunk;
    int end = base + chunk; if (end > E) end = E;
    for (int e = base + (int)threadIdx.x; e < end; e += 1024) {
        int s = node2slot[edge[E + e]];     // every e1 is sampled -> canonical slot
        rank16[e] = (unsigned short)atomicAdd(&hcnt[s], 1);
    }
    __syncthreads();
    int* crow = counts + (size_t)blockIdx.x * S;
    for (int i = threadIdx.x; i < S; i += 1024) crow[i] = hcnt[i];
}

// scan-only: counting-sort phase 2 fused with slot-prefix -> per-block bases, nseg, off.
// (cmat moved into place_kernel, where it hides under place's latency-bound streaming.)
__global__ __launch_bounds__(256)
void alloc_scan(int* __restrict__ counts, int* __restrict__ nseg,
                int* __restrict__ off, int* __restrict__ total, int S) {
    __shared__ int wsum[4];
    __shared__ int bb;
    const int tid = threadIdx.x;
    int s = blockIdx.x * 256 + tid;
    int v = 0;
    if (s < S) {
        int acc = 0;
        for (int b2 = 0; b2 < NB; ++b2) {       // column scan (coalesced across tid)
            size_t o = (size_t)b2 * S + s;
            int c = counts[o];
            counts[o] = acc;
            acc += c;
        }
        nseg[s] = acc;                           // dup slots get 0 automatically
        v = acc;
    }
    int lane = tid & 63, wv = tid >> 6;
    int sc = v;
    #pragma unroll
    for (int d = 1; d < 64; d <<= 1) {
        int t = __shfl_up(sc, d, 64);
        if (lane >= d) sc += t;
    }
    if (lane == 63) wsum[wv] = sc;
    __syncthreads();
    if (tid == 0) {
        int t = 0;
        #pragma unroll
        for (int i = 0; i < 4; ++i) { int w = wsum[i]; wsum[i] = t; t += w; }
        bb = atomicAdd(total, t);
    }
    __syncthreads();
    int excl = bb + wsum[wv] + sc - v;
    if (s < S) off[s] = excl;
}

// blocks [0,EB): ATOMIC-FREE placement p = off[slot]+blockbase[b][slot]+localrank
//   (threads [E,E+S) build snfo). blocks [EB,EB+CB): cmat = b + x[idx]·W1 -> out
//   (needs only xbf/w1t — ready after histx; hides under place's streaming).
__global__ __launch_bounds__(256)
void place_cmat(const int* __restrict__ edge, const float* __restrict__ pn,
                const int* __restrict__ node2slot,
                const unsigned short* __restrict__ rank16,
                const int* __restrict__ off, const int* __restrict__ counts,
                const int* __restrict__ nseg, const int* __restrict__ idx,
                const unsigned short* __restrict__ xbf,
                const unsigned short* __restrict__ w1t, const float* __restrict__ bias,
                uint4* __restrict__ prec, int2* __restrict__ snfo,
                float* __restrict__ out, int E, int S, int chunk, int EB) {
    __shared__ __align__(16) unsigned short a_lds[64 * LW1];
    const int tid = threadIdx.x;

    if ((int)blockIdx.x >= EB) {
        // ---- cmat role: 64 slots per block, A rows from xbf (already bf16) ----
        const int sbase = (blockIdx.x - EB) * 64;
        const int m = tid >> 2, p = tid & 3;
        {
            int s = sbase + m; if (s >= S) s = S - 1;
            int node = idx[s];
            const uint4* src = (const uint4*)(xbf + (size_t)node * F_DIM) + p * 2;
            uint4* dst = (uint4*)(a_lds + m * LW1 + p * 16);
            dst[0] = src[0]; dst[1] = src[1];
            if (p == 0) *(uint4*)(a_lds + m * LW1 + 64) = make_uint4(0, 0, 0, 0);
        }
        __syncthreads();
        const int wv = tid >> 6, lane = tid & 63, l15 = lane & 15, quad = lane >> 4;
        const int n0 = wv * 32 + l15, n1 = n0 + 16;
        f32x4 acc[4][2];
        #pragma unroll
        for (int i = 0; i < 4; ++i) {
            acc[i][0] = (f32x4){0.f, 0.f, 0.f, 0.f};
            acc[i][1] = (f32x4){0.f, 0.f, 0.f, 0.f};
        }
        #pragma unroll
        for (int ks = 0; ks < 2; ++ks) {
            const int ko = ks * 32 + quad * 8;
            short8 bf0 = *(const short8*)(w1t + (size_t)n0 * LW1 + ko);
            short8 bf1 = *(const short8*)(w1t + (size_t)n1 * LW1 + ko);
            #pragma unroll
            for (int mt = 0; mt < 4; ++mt) {
                short8 af = *(const short8*)(a_lds + (mt * 16 + l15) * LW1 + ko);
                acc[mt][0] = __builtin_amdgcn_mfma_f32_16x16x32_bf16(af, bf0, acc[mt][0], 0, 0, 0);
                acc[mt][1] = __builtin_amdgcn_mfma_f32_16x16x32_bf16(af, bf1, acc[mt][1], 0, 0, 0);
            }
        }
        const float b0 = bias[n0], b1 = bias[n1];
        #pragma unroll
        for (int mt = 0; mt < 4; ++mt) {
            #pragma unroll
            for (int r = 0; r < 4; ++r) {
                int s = sbase + mt * 16 + quad * 4 + r;     // C/D: row = quad*4 + reg
                if (s < S) {
                    out[(size_t)s * H_DIM + n0] = acc[mt][0][r] + b0;
                    out[(size_t)s * H_DIM + n1] = acc[mt][1][r] + b1;
                }
            }
        }
        return;
    }

    // ---- place role ----
    int g = blockIdx.x * 256 + tid;
    if (g >= E) {
        int s = g - E;
        if (s < S) {
            int sp = node2slot[idx[s]];
            snfo[s] = make_int2(off[sp], nseg[sp]);
        }
        return;
    }
    int e0 = edge[g], e1 = edge[E + g];
    int slot = node2slot[e1];
    int b = g / chunk;
    int p = off[slot] + counts[(size_t)b * S + slot] + (int)rank16[g];
    const float4* pn4 = (const float4*)pn;
    float4 p0a = pn4[(size_t)e0 * 2], p0b = pn4[(size_t)e0 * 2 + 1];
    float4 p1a = pn4[(size_t)e1 * 2], p1b = pn4[(size_t)e1 * 2 + 1];
    float px = p0a.x - p1a.x;
    float py = p0a.y - p1a.y;
    float pz = p0a.z - p1a.z;
    float n0x = p0a.w, n0y = p0b.x, n0z = p0b.y;
    float n1x = p1a.w, n1y = p1b.x, n1z = p1b.y;
    float d  = sqrtf(px * px + py * py + pz * pz);
    float a1 = angle3(n1x, n1y, n1z, px, py, pz);
    float a2 = angle3(n0x, n0y, n0z, px, py, pz);
    float a3 = angle3(n1x, n1y, n1z, n0x, n0y, n0z);
    uint4 rec;
    rec.x = (unsigned)e0;
    rec.y = pk(d, a1);
    rec.z = pk(a2, a3);
    rec.w = 0;
    prec[p] = rec;
}

__device__ __forceinline__ void load_af(uint4 rec, const unsigned short* __restrict__ xbf,
                                        int quad, short8& a0, short8& a1, short8& a2) {
    const short8* xr = (const short8*)(xbf + (size_t)rec.x * F_DIM);
    a0 = xr[quad];          // k = quad*8 .. +8
    a1 = xr[4 + quad];      // k = 32 + quad*8 .. +8
    short8 z = (short8){0, 0, 0, 0, 0, 0, 0, 0};
    if (quad == 0) {        // k = 64..67 = ppf, 68..71 zero (wt2 rows 68+ are zero anyway)
        z[0] = (short)(rec.y & 0xffff); z[1] = (short)(rec.y >> 16);
        z[2] = (short)(rec.z & 0xffff); z[3] = (short)(rec.z >> 16);
    }
    a2 = z;
}

// wave-per-segment, STATIC interleave; depth-2 record prefetch; snfo startup.
// R16: accumulator split into TWO passes of 4 cts (acc[4], -16 VGPR; A-frags stay in
// regs across passes; 4 independent MFMA chains still hide MFMA latency) to fit the
// __launch_bounds__(256,3) cap (~85 VGPR, 3 blocks = 12 waves/CU vs (256,2)'s 8 —
// R15 showed occupancy pinned at the (256,2) ceiling). R6/R8: (256,4)'s 64-cap spills.
__global__ __launch_bounds__(256, 3)
void seg_kernel(const unsigned short* __restrict__ xbf, const unsigned short* __restrict__ wt2,
                const uint4* __restrict__ prec, const int2* __restrict__ snfo,
                float* __restrict__ out, int S) {
    __shared__ __align__(16) unsigned short w_lds[H_DIM * LW2];
    {
        const uint4* src = (const uint4*)wt2;
        uint4* dst = (uint4*)w_lds;
        for (int g = threadIdx.x; g < H_DIM * LW2 / 8; g += 256) dst[g] = src[g];
    }
    __syncthreads();

    const int tid  = threadIdx.x;
    const int wv   = tid >> 6;
    const int lane = tid & 63;
    const int l15  = lane & 15;
    const int quad = lane >> 4;
    const int nw   = gridDim.x << 2;

    for (int s = (blockIdx.x << 2) + wv; s < S; s += nw) {
        const int2 nf = snfo[s];
        const int n = nf.y;
        float* orow = out + (size_t)s * H_DIM;
        if (n == 0) {                   // empty segment -> 0 (reference isfinite fixup)
            orow[lane] = 0.f;
            orow[64 + lane] = 0.f;
            continue;
        }
        const uint4* pb = prec + nf.x;

        float rm[8];
        #pragma unroll
        for (int ct = 0; ct < 8; ++ct) rm[ct] = -FLT_MAX;

        const int ntile = (n + 15) >> 4;
        int r0 = l15;      if (r0 >= n) r0 = n - 1;   // pad rows = real dup -> exact for max
        int r1 = 16 + l15; if (r1 >= n) r1 = n - 1;
        uint4 rec_c = pb[r0];
        uint4 rec_n = (ntile > 1) ? pb[r1] : rec_c;
        short8 a0c, a1c, a2c;
        load_af(rec_c, xbf, quad, a0c, a1c, a2c);

        for (int t = 0; t < ntile; ++t) {
            // rec two tiles ahead; A-frags one tile ahead from an already-resident rec
            uint4 rec_nn = rec_n;
            if (t + 2 < ntile) {
                int rn = ((t + 2) << 4) + l15; if (rn >= n) rn = n - 1;
                rec_nn = pb[rn];
            }
            short8 a0n, a1n, a2n;
            load_af(rec_n, xbf, quad, a0n, a1n, a2n);

            #pragma unroll
            for (int hp = 0; hp < 2; ++hp) {        // two 4-ct passes: acc[4] not acc[8]
                f32x4 acc[4];
                #pragma unroll
                for (int c4 = 0; c4 < 4; ++c4) acc[c4] = (f32x4){0.f, 0.f, 0.f, 0.f};
                #pragma unroll
                for (int c4 = 0; c4 < 4; ++c4) {
                    const int ct = hp * 4 + c4;
                    const unsigned short* wc = w_lds + (ct * 16 + l15) * LW2 + (quad << 3);
                    short8 b0 = *(const short8*)(wc);
                    short8 b1 = *(const short8*)(wc + 32);
                    short8 b2 = *(const short8*)(wc + 64);
                    acc[c4] = __builtin_amdgcn_mfma_f32_16x16x32_bf16(a0c, b0, acc[c4], 0, 0, 0);
                    acc[c4] = __builtin_amdgcn_mfma_f32_16x16x32_bf16(a1c, b1, acc[c4], 0, 0, 0);
                    acc[c4] = __builtin_amdgcn_mfma_f32_16x16x32_bf16(a2c, b2, acc[c4], 0, 0, 0);
                }
                #pragma unroll
                for (int c4 = 0; c4 < 4; ++c4)
                    rm[hp * 4 + c4] = fmaxf(rm[hp * 4 + c4],
                                            fmaxf(fmaxf(acc[c4][0], acc[c4][1]),
                                                  fmaxf(acc[c4][2], acc[c4][3])));
            }
            a0c = a0n; a1c = a1n; a2c = a2n;
            rec_n = rec_nn;
        }

        #pragma unroll
        for (int ct = 0; ct < 8; ++ct) {
            rm[ct] = fmaxf(rm[ct], __shfl_xor(rm[ct], 16, 64));
            rm[ct] = fmaxf(rm[ct], __shfl_xor(rm[ct], 32, 64));
        }
        float v0 = rm[0], v1 = rm[4];   // col = ct*16 + l15; lane -> cols lane, lane+64
        if (quad == 1)      { v0 = rm[1]; v1 = rm[5]; }
        else if (quad == 2) { v0 = rm[2]; v1 = rm[6]; }
        else if (quad == 3) { v0 = rm[3]; v1 = rm[7]; }
        orow[lane]      = fmaxf(orow[lane] + v0, 0.f);    // c + max, relu (hoist exact)
        orow[64 + lane] = fmaxf(orow[64 + lane] + v1, 0.f);
    }
}

extern "C" void kernel_launch(void* const* d_in, const int* in_sizes, int n_in,
                              void* d_out, int out_size, void* d_ws, size_t ws_size,
                              hipStream_t stream) {
    const float* x      = (const float*)d_in[0];
    const float* pos    = (const float*)d_in[1];
    const float* normal = (const float*)d_in[2];
    const float* W      = (const float*)d_in[3];
    const float* b      = (const float*)d_in[4];
    const int*   edge   = (const int*)d_in[5];
    const int*   idx    = (const int*)d_in[6];

    const int H = in_sizes[4];            // 128
    const int K = in_sizes[3] / H;        // 132
    const int F = (K - 4) / 2;            // 64
    const int N = in_sizes[0] / F;        // 100000
    const int E = in_sizes[5] / 2;        // 800000
    const int S = in_sizes[6];            // 25000  (SMAX=25600 LDS histogram bound)

    // ws (256B aligned): wt2 | w1t | xbf[N*64]bf16 | pn[N*8]f32 | prec[E]uint4
    //                    | node2slot[N] | rank16[E] | counts[NB*S] | nseg[S] | off[S]
    //                    | snfo[S] | total
    char* p = (char*)d_ws;
    auto alloc = [&](size_t bytes) { char* r = p; p += (bytes + 255) & ~(size_t)255; return r; };
    unsigned short* wt2 = (unsigned short*)alloc((size_t)H_DIM * LW2 * sizeof(unsigned short));
    unsigned short* w1t = (unsigned short*)alloc((size_t)H_DIM * LW1 * sizeof(unsigned short));
    unsigned short* xbf = (unsigned short*)alloc((size_t)N * F_DIM * sizeof(unsigned short));
    float* pn           = (float*)alloc((size_t)N * 8 * sizeof(float));
    uint4* prec         = (uint4*)alloc((size_t)E * sizeof(uint4));
    int* node2slot      = (int*)alloc((size_t)N * sizeof(int));
    unsigned short* rank16 = (unsigned short*)alloc((size_t)E * sizeof(unsigned short));
    int* counts         = (int*)alloc((size_t)NB * S * sizeof(int));
    int* nseg           = (int*)alloc((size_t)S * sizeof(int));
    int* off            = (int*)alloc((size_t)S * sizeof(int));
    int2* snfo          = (int2*)alloc((size_t)S * sizeof(int2));
    int* total          = (int*)alloc(sizeof(int));
    float* out = (float*)d_out;           // cmat writes c, seg RMWs to final result

    const int AB = (S + 255) / 256;
    const int CB = (S + 63) / 64;
    const int NF8 = N * F_DIM / 8;
    const int chunk = (E + NB - 1) / NB;  // 6250 (< 65536: rank16 fits u16)
    const int EB = (E + S + 255) / 256;

    prep_tiny<<<512, 256, 0, stream>>>(W, wt2, w1t, idx, node2slot, pos, out, S);
    histx<<<NB + SB, 1024, 0, stream>>>(edge, node2slot, rank16, counts, total,
                                        x, xbf, pos, normal, pn, E, S, chunk, N, NF8);
    alloc_scan<<<AB, 256, 0, stream>>>(counts, nseg, off, total, S);
    place_cmat<<<EB + CB, 256, 0, stream>>>(edge, pn, node2slot, rank16, off, counts,
                                            nseg, idx, xbf, w1t, b, prec, snfo, out,
                                            E, S, chunk, EB);
    seg_kernel<<<2048, 256, 0, stream>>>(xbf, wt2, prec, snfo, out, S);
}